// Round 1
// baseline (72.543 us; speedup 1.0000x reference)
//
#include <hip/hip_runtime.h>

#define SL1_BETA 0.01f

__device__ __forceinline__ float smooth_l1(float x) {
    float d = fabsf(x);
    return (d < SL1_BETA) ? (0.5f * d * d / SL1_BETA) : (d - 0.5f * SL1_BETA);
}

__device__ __forceinline__ void quat_to_mat(float4 q, float R[9]) {
    float r = q.x, i = q.y, j = q.z, k = q.w;
    float two_s = 2.0f / (r*r + i*i + j*j + k*k);
    R[0] = 1.0f - two_s * (j*j + k*k);
    R[1] = two_s * (i*j - k*r);
    R[2] = two_s * (i*k + j*r);
    R[3] = two_s * (i*j + k*r);
    R[4] = 1.0f - two_s * (i*i + k*k);
    R[5] = two_s * (j*k - i*r);
    R[6] = two_s * (i*k - j*r);
    R[7] = two_s * (j*k + i*r);
    R[8] = 1.0f - two_s * (i*i + j*j);
}

__global__ __launch_bounds__(256) void euler_loss_kernel(
        const float*  __restrict__ tt,   // target_transl (b,3)
        const float4* __restrict__ tq,   // target_rot    (b,4)
        const float*  __restrict__ te,   // transl_err    (b,3)
        const float4* __restrict__ qe,   // rot_err       (b,4)
        double* __restrict__ acc, int b) {
    float sr = 0.0f, st = 0.0f;
    int stride = gridDim.x * blockDim.x;
    for (int idx = blockIdx.x * blockDim.x + threadIdx.x; idx < b; idx += stride) {
        float4 q = tq[idx];
        float R[9];
        quat_to_mat(q, R);
        float4 e = qe[idx];
        float P[9];
        quat_to_mat(e, P);

        // loss_r: sum smooth_l1(R^T P - I)
        #pragma unroll
        for (int i2 = 0; i2 < 3; ++i2) {
            #pragma unroll
            for (int j2 = 0; j2 < 3; ++j2) {
                float v = R[0*3 + i2] * P[0*3 + j2]
                        + R[1*3 + i2] * P[1*3 + j2]
                        + R[2*3 + i2] * P[2*3 + j2];
                sr += smooth_l1(v - (i2 == j2 ? 1.0f : 0.0f));
            }
        }

        float t0 = tt[3*idx + 0], t1 = tt[3*idx + 1], t2 = tt[3*idx + 2];
        // T_inv = -R^T t
        float Ti0 = -(R[0]*t0 + R[3]*t1 + R[6]*t2);
        float Ti1 = -(R[1]*t0 + R[4]*t1 + R[7]*t2);
        float Ti2 = -(R[2]*t0 + R[5]*t1 + R[8]*t2);

        float p0 = te[3*idx + 0], p1 = te[3*idx + 1], p2 = te[3*idx + 2];
        st += smooth_l1(P[0]*Ti0 + P[1]*Ti1 + P[2]*Ti2 + p0);
        st += smooth_l1(P[3]*Ti0 + P[4]*Ti1 + P[5]*Ti2 + p1);
        st += smooth_l1(P[6]*Ti0 + P[7]*Ti1 + P[8]*Ti2 + p2);
    }

    // wave (64-lane) reduction
    #pragma unroll
    for (int off = 32; off > 0; off >>= 1) {
        sr += __shfl_down(sr, off);
        st += __shfl_down(st, off);
    }
    __shared__ float s_r[4], s_t[4];   // 256 threads = 4 waves
    int lane = threadIdx.x & 63;
    int wid  = threadIdx.x >> 6;
    if (lane == 0) { s_r[wid] = sr; s_t[wid] = st; }
    __syncthreads();
    if (threadIdx.x == 0) {
        float br = s_r[0] + s_r[1] + s_r[2] + s_r[3];
        float bt = s_t[0] + s_t[1] + s_t[2] + s_t[3];
        atomicAdd(&acc[0], (double)br);
        atomicAdd(&acc[1], (double)bt);
    }
}

__global__ void euler_loss_finalize(const double* __restrict__ acc,
                                    float* __restrict__ out, int b) {
    double inv_b = 1.0 / (double)b;
    double lr = acc[0] * inv_b;
    double lt = acc[1] * inv_b;
    out[0] = (float)(lr + lt);
    out[1] = (float)lt;
    out[2] = (float)lr;
}

extern "C" void kernel_launch(void* const* d_in, const int* in_sizes, int n_in,
                              void* d_out, int out_size, void* d_ws, size_t ws_size,
                              hipStream_t stream) {
    // input order: point_clouds(0, unused), target_transl(1), target_rot(2),
    //              transl_err(3), rot_err(4)
    const float*  tt = (const float*)d_in[1];
    const float4* tq = (const float4*)d_in[2];
    const float*  te = (const float*)d_in[3];
    const float4* qe = (const float4*)d_in[4];
    float* out = (float*)d_out;
    int b = in_sizes[1] / 3;

    double* acc = (double*)d_ws;
    hipMemsetAsync(acc, 0, 2 * sizeof(double), stream);

    int block = 256;
    int grid = 2048;   // grid-stride; ~4 samples/thread at b=2M
    euler_loss_kernel<<<grid, block, 0, stream>>>(tt, tq, te, qe, acc, b);
    euler_loss_finalize<<<1, 1, 0, stream>>>(acc, out, b);
}

// Round 2
// 60.437 us; speedup vs baseline: 1.2003x; 1.2003x over previous
//
#include <hip/hip_runtime.h>

#define SL1_BETA 0.01f
#define NSLOT 32   // atomic contention spreading

__device__ __forceinline__ float smooth_l1(float x) {
    float d = fabsf(x);
    return (d < SL1_BETA) ? (0.5f * d * d / SL1_BETA) : (d - 0.5f * SL1_BETA);
}

__device__ __forceinline__ void quat_to_mat(float4 q, float R[9]) {
    float r = q.x, i = q.y, j = q.z, k = q.w;
    float two_s = 2.0f / (r*r + i*i + j*j + k*k);
    R[0] = 1.0f - two_s * (j*j + k*k);
    R[1] = two_s * (i*j - k*r);
    R[2] = two_s * (i*k + j*r);
    R[3] = two_s * (i*j + k*r);
    R[4] = 1.0f - two_s * (i*i + k*k);
    R[5] = two_s * (j*k - i*r);
    R[6] = two_s * (i*k - j*r);
    R[7] = two_s * (j*k + i*r);
    R[8] = 1.0f - two_s * (i*i + j*j);
}

__global__ __launch_bounds__(256) void euler_loss_kernel(
        const float*  __restrict__ tt,   // target_transl (b,3)
        const float4* __restrict__ tq,   // target_rot    (b,4)
        const float*  __restrict__ te,   // transl_err    (b,3)
        const float4* __restrict__ qe,   // rot_err       (b,4)
        double* __restrict__ acc, int b) {
    int idx = blockIdx.x * blockDim.x + threadIdx.x;
    float sr = 0.0f, st = 0.0f;
    if (idx < b) {
        // Issue ALL loads up front — no loop-carried dependency, full MLP.
        float4 q  = tq[idx];
        float4 e  = qe[idx];
        float  t0 = tt[3*idx + 0], t1 = tt[3*idx + 1], t2 = tt[3*idx + 2];
        float  p0 = te[3*idx + 0], p1 = te[3*idx + 1], p2 = te[3*idx + 2];

        float R[9], P[9];
        quat_to_mat(q, R);
        quat_to_mat(e, P);

        // loss_r: sum smooth_l1(R^T P - I)
        #pragma unroll
        for (int i2 = 0; i2 < 3; ++i2) {
            #pragma unroll
            for (int j2 = 0; j2 < 3; ++j2) {
                float v = R[0*3 + i2] * P[0*3 + j2]
                        + R[1*3 + i2] * P[1*3 + j2]
                        + R[2*3 + i2] * P[2*3 + j2];
                sr += smooth_l1(v - (i2 == j2 ? 1.0f : 0.0f));
            }
        }

        // T_inv = -R^T t
        float Ti0 = -(R[0]*t0 + R[3]*t1 + R[6]*t2);
        float Ti1 = -(R[1]*t0 + R[4]*t1 + R[7]*t2);
        float Ti2 = -(R[2]*t0 + R[5]*t1 + R[8]*t2);

        st += smooth_l1(P[0]*Ti0 + P[1]*Ti1 + P[2]*Ti2 + p0);
        st += smooth_l1(P[3]*Ti0 + P[4]*Ti1 + P[5]*Ti2 + p1);
        st += smooth_l1(P[6]*Ti0 + P[7]*Ti1 + P[8]*Ti2 + p2);
    }

    // wave (64-lane) reduction
    #pragma unroll
    for (int off = 32; off > 0; off >>= 1) {
        sr += __shfl_down(sr, off);
        st += __shfl_down(st, off);
    }
    __shared__ float s_r[4], s_t[4];   // 256 threads = 4 waves
    int lane = threadIdx.x & 63;
    int wid  = threadIdx.x >> 6;
    if (lane == 0) { s_r[wid] = sr; s_t[wid] = st; }
    __syncthreads();
    if (threadIdx.x == 0) {
        float br = s_r[0] + s_r[1] + s_r[2] + s_r[3];
        float bt = s_t[0] + s_t[1] + s_t[2] + s_t[3];
        int slot = blockIdx.x & (NSLOT - 1);
        atomicAdd(&acc[slot],         (double)br);
        atomicAdd(&acc[NSLOT + slot], (double)bt);
    }
}

__global__ void euler_loss_finalize(const double* __restrict__ acc,
                                    float* __restrict__ out, int b) {
    double sr = 0.0, st = 0.0;
    for (int i = 0; i < NSLOT; ++i) { sr += acc[i]; st += acc[NSLOT + i]; }
    double inv_b = 1.0 / (double)b;
    double lr = sr * inv_b;
    double lt = st * inv_b;
    out[0] = (float)(lr + lt);
    out[1] = (float)lt;
    out[2] = (float)lr;
}

extern "C" void kernel_launch(void* const* d_in, const int* in_sizes, int n_in,
                              void* d_out, int out_size, void* d_ws, size_t ws_size,
                              hipStream_t stream) {
    // input order: point_clouds(0, unused), target_transl(1), target_rot(2),
    //              transl_err(3), rot_err(4)
    const float*  tt = (const float*)d_in[1];
    const float4* tq = (const float4*)d_in[2];
    const float*  te = (const float*)d_in[3];
    const float4* qe = (const float4*)d_in[4];
    float* out = (float*)d_out;
    int b = in_sizes[1] / 3;

    double* acc = (double*)d_ws;
    hipMemsetAsync(acc, 0, 2 * NSLOT * sizeof(double), stream);

    int block = 256;
    int grid = (b + block - 1) / block;   // 1 sample per thread
    euler_loss_kernel<<<grid, block, 0, stream>>>(tt, tq, te, qe, acc, b);
    euler_loss_finalize<<<1, 1, 0, stream>>>(acc, out, b);
}

// Round 3
// 45.686 us; speedup vs baseline: 1.5878x; 1.3229x over previous
//
#include <hip/hip_runtime.h>

#define SL1_BETA 0.01f
#define NSLOT 64   // atomic contention spreading (per-wave atomics)

__device__ __forceinline__ float smooth_l1(float x) {
    float d = fabsf(x);
    return (d < SL1_BETA) ? (0.5f * d * d / SL1_BETA) : (d - 0.5f * SL1_BETA);
}

__device__ __forceinline__ void quat_to_mat(float4 q, float R[9]) {
    float r = q.x, i = q.y, j = q.z, k = q.w;
    float two_s = 2.0f / (r*r + i*i + j*j + k*k);
    R[0] = 1.0f - two_s * (j*j + k*k);
    R[1] = two_s * (i*j - k*r);
    R[2] = two_s * (i*k + j*r);
    R[3] = two_s * (i*j + k*r);
    R[4] = 1.0f - two_s * (i*i + k*k);
    R[5] = two_s * (j*k - i*r);
    R[6] = two_s * (j*k + i*r) * 0.0f + two_s * (j*k - i*r) * 0.0f + two_s * (j*k - i*r); // placeholder avoided below
    R[7] = two_s * (j*k + i*r);
    R[8] = 1.0f - two_s * (i*i + j*j);
}

// NOTE: fixed version (R[5]/R[6] correct) — the one actually used:
__device__ __forceinline__ void quat_to_mat9(float4 q, float R[9]) {
    float r = q.x, i = q.y, j = q.z, k = q.w;
    float two_s = 2.0f / (r*r + i*i + j*j + k*k);
    R[0] = 1.0f - two_s * (j*j + k*k);
    R[1] = two_s * (i*j - k*r);
    R[2] = two_s * (i*k + j*r);
    R[3] = two_s * (i*j + k*r);
    R[4] = 1.0f - two_s * (i*i + k*k);
    R[5] = two_s * (j*k - i*r);
    R[6] = two_s * (i*k - j*r);
    R[7] = two_s * (j*k + i*r);
    R[8] = 1.0f - two_s * (i*i + j*j);
}

__device__ __forceinline__ void sample_loss(float4 q, float4 e,
                                            float t0, float t1, float t2,
                                            float p0, float p1, float p2,
                                            float& sr, float& st) {
    float R[9], P[9];
    quat_to_mat9(q, R);
    quat_to_mat9(e, P);

    // loss_r: sum smooth_l1(R^T P - I)
    #pragma unroll
    for (int i2 = 0; i2 < 3; ++i2) {
        #pragma unroll
        for (int j2 = 0; j2 < 3; ++j2) {
            float v = R[0*3 + i2] * P[0*3 + j2]
                    + R[1*3 + i2] * P[1*3 + j2]
                    + R[2*3 + i2] * P[2*3 + j2];
            sr += smooth_l1(v - (i2 == j2 ? 1.0f : 0.0f));
        }
    }

    // T_inv = -R^T t
    float Ti0 = -(R[0]*t0 + R[3]*t1 + R[6]*t2);
    float Ti1 = -(R[1]*t0 + R[4]*t1 + R[7]*t2);
    float Ti2 = -(R[2]*t0 + R[5]*t1 + R[8]*t2);

    st += smooth_l1(P[0]*Ti0 + P[1]*Ti1 + P[2]*Ti2 + p0);
    st += smooth_l1(P[3]*Ti0 + P[4]*Ti1 + P[5]*Ti2 + p1);
    st += smooth_l1(P[6]*Ti0 + P[7]*Ti1 + P[8]*Ti2 + p2);
}

__global__ __launch_bounds__(256) void euler_loss_kernel(
        const float4* __restrict__ tt4,  // target_transl (b,3) as float4 (b%4==0)
        const float4* __restrict__ tq,   // target_rot    (b,4)
        const float4* __restrict__ te4,  // transl_err    (b,3) as float4
        const float4* __restrict__ qe,   // rot_err       (b,4)
        double* __restrict__ acc, int nquad) {
    int g = blockIdx.x * blockDim.x + threadIdx.x;   // quad index
    float sr = 0.0f, st = 0.0f;
    if (g < nquad) {
        // 14 independent float4 loads — all issued before any use.
        float4 q0 = tq[4*g+0], q1 = tq[4*g+1], q2 = tq[4*g+2], q3 = tq[4*g+3];
        float4 e0 = qe[4*g+0], e1 = qe[4*g+1], e2 = qe[4*g+2], e3 = qe[4*g+3];
        float4 ta = tt4[3*g+0], tb = tt4[3*g+1], tc = tt4[3*g+2];
        float4 pa = te4[3*g+0], pb = te4[3*g+1], pc = te4[3*g+2];

        sample_loss(q0, e0, ta.x, ta.y, ta.z, pa.x, pa.y, pa.z, sr, st);
        sample_loss(q1, e1, ta.w, tb.x, tb.y, pa.w, pb.x, pb.y, sr, st);
        sample_loss(q2, e2, tb.z, tb.w, tc.x, pb.z, pb.w, pc.x, sr, st);
        sample_loss(q3, e3, tc.y, tc.z, tc.w, pc.y, pc.z, pc.w, sr, st);
    }

    // wave (64-lane) reduction, then one atomic per wave (no LDS, no barrier)
    #pragma unroll
    for (int off = 32; off > 0; off >>= 1) {
        sr += __shfl_down(sr, off);
        st += __shfl_down(st, off);
    }
    int lane = threadIdx.x & 63;
    if (lane == 0) {
        int wid  = threadIdx.x >> 6;
        int slot = (blockIdx.x * (blockDim.x >> 6) + wid) & (NSLOT - 1);
        atomicAdd(&acc[2*slot + 0], (double)sr);
        atomicAdd(&acc[2*slot + 1], (double)st);
    }
}

__global__ void euler_loss_finalize(const double* __restrict__ acc,
                                    float* __restrict__ out, int b) {
    double sr = 0.0, st = 0.0;
    for (int i = 0; i < NSLOT; ++i) { sr += acc[2*i]; st += acc[2*i + 1]; }
    double inv_b = 1.0 / (double)b;
    double lr = sr * inv_b;
    double lt = st * inv_b;
    out[0] = (float)(lr + lt);
    out[1] = (float)lt;
    out[2] = (float)lr;
}

extern "C" void kernel_launch(void* const* d_in, const int* in_sizes, int n_in,
                              void* d_out, int out_size, void* d_ws, size_t ws_size,
                              hipStream_t stream) {
    // input order: point_clouds(0, unused), target_transl(1), target_rot(2),
    //              transl_err(3), rot_err(4)
    const float4* tt4 = (const float4*)d_in[1];
    const float4* tq  = (const float4*)d_in[2];
    const float4* te4 = (const float4*)d_in[3];
    const float4* qe  = (const float4*)d_in[4];
    float* out = (float*)d_out;
    int b = in_sizes[1] / 3;        // 2097152 (divisible by 4)
    int nquad = b / 4;

    double* acc = (double*)d_ws;
    hipMemsetAsync(acc, 0, 2 * NSLOT * sizeof(double), stream);

    int block = 256;
    int grid = (nquad + block - 1) / block;   // 2048 blocks at b=2M
    euler_loss_kernel<<<grid, block, 0, stream>>>(tt4, tq, te4, qe, acc, nquad);
    euler_loss_finalize<<<1, 1, 0, stream>>>(acc, out, b);
}

// Round 4
// 45.222 us; speedup vs baseline: 1.6041x; 1.0103x over previous
//
#include <hip/hip_runtime.h>

#define SL1_BETA 0.01f
#define NSLOT 64   // atomic contention spreading (per-wave atomics)

__device__ __forceinline__ float smooth_l1(float x) {
    float d = fabsf(x);
    return (d < SL1_BETA) ? (0.5f * d * d / SL1_BETA) : (d - 0.5f * SL1_BETA);
}

__device__ __forceinline__ void quat_to_mat9(float4 q, float R[9]) {
    float r = q.x, i = q.y, j = q.z, k = q.w;
    float two_s = 2.0f / (r*r + i*i + j*j + k*k);
    R[0] = 1.0f - two_s * (j*j + k*k);
    R[1] = two_s * (i*j - k*r);
    R[2] = two_s * (i*k + j*r);
    R[3] = two_s * (i*j + k*r);
    R[4] = 1.0f - two_s * (i*i + k*k);
    R[5] = two_s * (j*k - i*r);
    R[6] = two_s * (i*k - j*r);
    R[7] = two_s * (j*k + i*r);
    R[8] = 1.0f - two_s * (i*i + j*j);
}

__device__ __forceinline__ void sample_loss(float4 q, float4 e,
                                            float t0, float t1, float t2,
                                            float p0, float p1, float p2,
                                            float& sr, float& st) {
    float R[9], P[9];
    quat_to_mat9(q, R);
    quat_to_mat9(e, P);

    // loss_r: sum smooth_l1(R^T P - I)
    #pragma unroll
    for (int i2 = 0; i2 < 3; ++i2) {
        #pragma unroll
        for (int j2 = 0; j2 < 3; ++j2) {
            float v = R[0*3 + i2] * P[0*3 + j2]
                    + R[1*3 + i2] * P[1*3 + j2]
                    + R[2*3 + i2] * P[2*3 + j2];
            sr += smooth_l1(v - (i2 == j2 ? 1.0f : 0.0f));
        }
    }

    // T_inv = -R^T t
    float Ti0 = -(R[0]*t0 + R[3]*t1 + R[6]*t2);
    float Ti1 = -(R[1]*t0 + R[4]*t1 + R[7]*t2);
    float Ti2 = -(R[2]*t0 + R[5]*t1 + R[8]*t2);

    st += smooth_l1(P[0]*Ti0 + P[1]*Ti1 + P[2]*Ti2 + p0);
    st += smooth_l1(P[3]*Ti0 + P[4]*Ti1 + P[5]*Ti2 + p1);
    st += smooth_l1(P[6]*Ti0 + P[7]*Ti1 + P[8]*Ti2 + p2);
}

// Block covers 1024 contiguous samples; thread t handles samples
// base + t + {0,256,512,768}.  Sample->thread permutation is irrelevant
// (global sum), and this makes every quat load a perfectly coalesced
// float4 (lane stride 16B) instead of stride-64B.
__global__ __launch_bounds__(256) void euler_loss_kernel(
        const float*  __restrict__ tt,   // target_transl (b,3)
        const float4* __restrict__ tq,   // target_rot    (b,4)
        const float*  __restrict__ te,   // transl_err    (b,3)
        const float4* __restrict__ qe,   // rot_err       (b,4)
        double* __restrict__ acc, int b) {
    int t    = threadIdx.x;
    int base = blockIdx.x * 1024;
    int s0 = base + t, s1 = s0 + 256, s2 = s0 + 512, s3 = s0 + 768;

    float sr = 0.0f, st = 0.0f;
    if (s3 < b) {   // full block (b % 1024 == 0 in practice)
        // Coalesced quat loads — 8 x float4, lane stride 16B.
        float4 q0 = tq[s0], q1 = tq[s1], q2 = tq[s2], q3 = tq[s3];
        float4 e0 = qe[s0], e1 = qe[s1], e2 = qe[s2], e3 = qe[s3];
        // (b,3) arrays: scalar loads, lane stride 12B; 3 components reuse lines in L1.
        float ta0 = tt[3*s0], ta1 = tt[3*s0+1], ta2 = tt[3*s0+2];
        float tb0 = tt[3*s1], tb1 = tt[3*s1+1], tb2 = tt[3*s1+2];
        float tc0 = tt[3*s2], tc1 = tt[3*s2+1], tc2 = tt[3*s2+2];
        float td0 = tt[3*s3], td1 = tt[3*s3+1], td2 = tt[3*s3+2];
        float pa0 = te[3*s0], pa1 = te[3*s0+1], pa2 = te[3*s0+2];
        float pb0 = te[3*s1], pb1 = te[3*s1+1], pb2 = te[3*s1+2];
        float pc0 = te[3*s2], pc1 = te[3*s2+1], pc2 = te[3*s2+2];
        float pd0 = te[3*s3], pd1 = te[3*s3+1], pd2 = te[3*s3+2];

        sample_loss(q0, e0, ta0, ta1, ta2, pa0, pa1, pa2, sr, st);
        sample_loss(q1, e1, tb0, tb1, tb2, pb0, pb1, pb2, sr, st);
        sample_loss(q2, e2, tc0, tc1, tc2, pc0, pc1, pc2, sr, st);
        sample_loss(q3, e3, td0, td1, td2, pd0, pd1, pd2, sr, st);
    } else {
        // tail-safe path (not hit at b = 2^21)
        int ss[4] = {s0, s1, s2, s3};
        for (int u = 0; u < 4; ++u) {
            int s = ss[u];
            if (s < b) {
                sample_loss(tq[s], qe[s], tt[3*s], tt[3*s+1], tt[3*s+2],
                            te[3*s], te[3*s+1], te[3*s+2], sr, st);
            }
        }
    }

    // wave (64-lane) reduction, then one atomic per wave (no LDS, no barrier)
    #pragma unroll
    for (int off = 32; off > 0; off >>= 1) {
        sr += __shfl_down(sr, off);
        st += __shfl_down(st, off);
    }
    int lane = threadIdx.x & 63;
    if (lane == 0) {
        int wid  = threadIdx.x >> 6;
        int slot = (blockIdx.x * (blockDim.x >> 6) + wid) & (NSLOT - 1);
        atomicAdd(&acc[2*slot + 0], (double)sr);
        atomicAdd(&acc[2*slot + 1], (double)st);
    }
}

__global__ void euler_loss_finalize(const double* __restrict__ acc,
                                    float* __restrict__ out, int b) {
    double sr = 0.0, st = 0.0;
    for (int i = 0; i < NSLOT; ++i) { sr += acc[2*i]; st += acc[2*i + 1]; }
    double inv_b = 1.0 / (double)b;
    double lr = sr * inv_b;
    double lt = st * inv_b;
    out[0] = (float)(lr + lt);
    out[1] = (float)lt;
    out[2] = (float)lr;
}

extern "C" void kernel_launch(void* const* d_in, const int* in_sizes, int n_in,
                              void* d_out, int out_size, void* d_ws, size_t ws_size,
                              hipStream_t stream) {
    // input order: point_clouds(0, unused), target_transl(1), target_rot(2),
    //              transl_err(3), rot_err(4)
    const float*  tt = (const float*)d_in[1];
    const float4* tq = (const float4*)d_in[2];
    const float*  te = (const float*)d_in[3];
    const float4* qe = (const float4*)d_in[4];
    float* out = (float*)d_out;
    int b = in_sizes[1] / 3;        // 2097152

    double* acc = (double*)d_ws;
    hipMemsetAsync(acc, 0, 2 * NSLOT * sizeof(double), stream);

    int block = 256;
    int grid = (b + 1023) / 1024;   // 1024 samples per block, 4 per thread
    euler_loss_kernel<<<grid, block, 0, stream>>>(tt, tq, te, qe, acc, b);
    euler_loss_finalize<<<1, 1, 0, stream>>>(acc, out, b);
}

// Round 5
// 34.048 us; speedup vs baseline: 2.1306x; 1.3282x over previous
//
#include <hip/hip_runtime.h>

#define SL1_BETA 0.01f
#define NSLOT   256            // one 128B line per slot (padded)
#define CHUNK   512            // samples per block
#define LDS_TQ  0              // 512 * 16 B = 8192
#define LDS_QE  8192           // 8192
#define LDS_TT  16384          // 512 * 12 B = 6144
#define LDS_TE  22528          // 6144
#define LDS_BYTES 28672        // 28 KB total

#define AS1(p) ((const __attribute__((address_space(1))) void*)(p))
#define AS3(p) ((__attribute__((address_space(3))) void*)(p))

__device__ __forceinline__ float smooth_l1(float x) {
    float d = fabsf(x);
    return (d < SL1_BETA) ? (0.5f * d * d / SL1_BETA) : (d - 0.5f * SL1_BETA);
}

__device__ __forceinline__ void quat_to_mat9(float4 q, float R[9]) {
    float r = q.x, i = q.y, j = q.z, k = q.w;
    float two_s = 2.0f / (r*r + i*i + j*j + k*k);
    R[0] = 1.0f - two_s * (j*j + k*k);
    R[1] = two_s * (i*j - k*r);
    R[2] = two_s * (i*k + j*r);
    R[3] = two_s * (i*j + k*r);
    R[4] = 1.0f - two_s * (i*i + k*k);
    R[5] = two_s * (j*k - i*r);
    R[6] = two_s * (i*k - j*r);
    R[7] = two_s * (j*k + i*r);
    R[8] = 1.0f - two_s * (i*i + j*j);
}

__device__ __forceinline__ void sample_loss(float4 q, float4 e,
                                            float t0, float t1, float t2,
                                            float p0, float p1, float p2,
                                            float& sr, float& st) {
    float R[9], P[9];
    quat_to_mat9(q, R);
    quat_to_mat9(e, P);

    // loss_r: sum smooth_l1(R^T P - I)
    #pragma unroll
    for (int i2 = 0; i2 < 3; ++i2) {
        #pragma unroll
        for (int j2 = 0; j2 < 3; ++j2) {
            float v = R[0*3 + i2] * P[0*3 + j2]
                    + R[1*3 + i2] * P[1*3 + j2]
                    + R[2*3 + i2] * P[2*3 + j2];
            sr += smooth_l1(v - (i2 == j2 ? 1.0f : 0.0f));
        }
    }

    // T_inv = -R^T t
    float Ti0 = -(R[0]*t0 + R[3]*t1 + R[6]*t2);
    float Ti1 = -(R[1]*t0 + R[4]*t1 + R[7]*t2);
    float Ti2 = -(R[2]*t0 + R[5]*t1 + R[8]*t2);

    st += smooth_l1(P[0]*Ti0 + P[1]*Ti1 + P[2]*Ti2 + p0);
    st += smooth_l1(P[3]*Ti0 + P[4]*Ti1 + P[5]*Ti2 + p1);
    st += smooth_l1(P[6]*Ti0 + P[7]*Ti1 + P[8]*Ti2 + p2);
}

// Each block: DMA-stage its 28 KB slice [tq|qe|tt|te] of CHUNK=512 samples
// into LDS via global_load_lds (fire-and-forget, 7 instr/wave), sync once,
// compute 2 samples/thread from LDS. 5 blocks/CU co-resident provide the
// DMA<->compute overlap.
__global__ __launch_bounds__(256) void euler_loss_kernel(
        const float*  __restrict__ tt,   // target_transl (b,3)
        const float4* __restrict__ tq,   // target_rot    (b,4)
        const float*  __restrict__ te,   // transl_err    (b,3)
        const float4* __restrict__ qe,   // rot_err       (b,4)
        double* __restrict__ acc, int b) {
    __shared__ __align__(16) unsigned char smem[LDS_BYTES];
    int t    = threadIdx.x;
    int lane = t & 63;
    int wid  = t >> 6;
    long long base = (long long)blockIdx.x * CHUNK;

    float sr = 0.0f, st = 0.0f;
    bool full = (base + CHUNK <= (long long)b);   // block-uniform
    if (full) {
        // ---- stage: 28 ops total, 7 per wave; 1 KB per op (64 lanes x 16 B)
        #pragma unroll
        for (int u = 0; u < 7; ++u) {
            int o = wid * 7 + u;                         // wave-uniform
            const unsigned char* src;
            if (o < 8)       src = (const unsigned char*)tq + base * 16 + (size_t)o        * 1024;
            else if (o < 16) src = (const unsigned char*)qe + base * 16 + (size_t)(o - 8)  * 1024;
            else if (o < 22) src = (const unsigned char*)tt + base * 12 + (size_t)(o - 16) * 1024;
            else             src = (const unsigned char*)te + base * 12 + (size_t)(o - 22) * 1024;
            __builtin_amdgcn_global_load_lds(AS1(src + (size_t)lane * 16),
                                             AS3(&smem[(size_t)o * 1024]),
                                             16, 0, 0);
        }
        __syncthreads();   // compiler emits vmcnt(0) drain + barrier

        const float4* tqL = (const float4*)&smem[LDS_TQ];
        const float4* qeL = (const float4*)&smem[LDS_QE];
        const float*  ttL = (const float*) &smem[LDS_TT];
        const float*  teL = (const float*) &smem[LDS_TE];
        #pragma unroll
        for (int u = 0; u < 2; ++u) {
            int c = t + u * 256;
            sample_loss(tqL[c], qeL[c],
                        ttL[3*c], ttL[3*c+1], ttL[3*c+2],
                        teL[3*c], teL[3*c+1], teL[3*c+2], sr, st);
        }
    } else {
        // tail block (not hit at b = 2^21): direct global loads
        for (long long s = base + t; s < (long long)b; s += 256) {
            sample_loss(tq[s], qe[s],
                        tt[3*s], tt[3*s+1], tt[3*s+2],
                        te[3*s], te[3*s+1], te[3*s+2], sr, st);
        }
    }

    // wave (64-lane) reduction, one atomic pair per wave
    #pragma unroll
    for (int off = 32; off > 0; off >>= 1) {
        sr += __shfl_down(sr, off);
        st += __shfl_down(st, off);
    }
    if (lane == 0) {
        int slot = (blockIdx.x * 4 + wid) & (NSLOT - 1);
        double* sp = (double*)((unsigned char*)acc + (size_t)slot * 128);  // 1 line/slot
        atomicAdd(&sp[0], (double)sr);
        atomicAdd(&sp[1], (double)st);
    }
}

__global__ __launch_bounds__(256) void euler_loss_finalize(
        const double* __restrict__ acc, float* __restrict__ out, int b) {
    int t = threadIdx.x;                 // 256 threads, one slot each
    const double* sp = (const double*)((const unsigned char*)acc + (size_t)t * 128);
    double sr = sp[0], st = sp[1];
    #pragma unroll
    for (int off = 32; off > 0; off >>= 1) {
        sr += __shfl_down(sr, off);
        st += __shfl_down(st, off);
    }
    __shared__ double s_r[4], s_t[4];
    int lane = t & 63, wid = t >> 6;
    if (lane == 0) { s_r[wid] = sr; s_t[wid] = st; }
    __syncthreads();
    if (t == 0) {
        double tr = s_r[0] + s_r[1] + s_r[2] + s_r[3];
        double tts = s_t[0] + s_t[1] + s_t[2] + s_t[3];
        double inv_b = 1.0 / (double)b;
        double lr = tr * inv_b;
        double lt = tts * inv_b;
        out[0] = (float)(lr + lt);
        out[1] = (float)lt;
        out[2] = (float)lr;
    }
}

extern "C" void kernel_launch(void* const* d_in, const int* in_sizes, int n_in,
                              void* d_out, int out_size, void* d_ws, size_t ws_size,
                              hipStream_t stream) {
    // input order: point_clouds(0, unused), target_transl(1), target_rot(2),
    //              transl_err(3), rot_err(4)
    const float*  tt = (const float*)d_in[1];
    const float4* tq = (const float4*)d_in[2];
    const float*  te = (const float*)d_in[3];
    const float4* qe = (const float4*)d_in[4];
    float* out = (float*)d_out;
    int b = in_sizes[1] / 3;             // 2097152

    double* acc = (double*)d_ws;
    hipMemsetAsync(acc, 0, (size_t)NSLOT * 128, stream);   // 32 KB of slots

    int grid = (b + CHUNK - 1) / CHUNK;  // 4096 blocks at b = 2^21
    euler_loss_kernel<<<grid, 256, 0, stream>>>(tt, tq, te, qe, acc, b);
    euler_loss_finalize<<<1, 256, 0, stream>>>(acc, out, b);
}